// Round 12
// baseline (90.150 us; speedup 1.0000x reference)
//
#include <hip/hip_runtime.h>

#define NR 4096      // rows per batch
#define DD 512       // feature dim
#define TWO_N 8192
#define MT2 32       // 8192/256 tiles per dim
#define NT2 528      // MT2*(MT2+1)/2
#define CH2 66       // NT2/8 per XCD

using bf16x8 = __attribute__((ext_vector_type(8))) short;   // 8 bf16 in 4 VGPRs
using f32x4  = __attribute__((ext_vector_type(4))) float;

__device__ __forceinline__ unsigned short f2bf(float f) {
    union { float f; unsigned u; } v; v.f = f;
    unsigned r = v.u + 0x7fff + ((v.u >> 16) & 1);   // round-to-nearest-even
    return (unsigned short)(r >> 16);
}

// Kernel 1: L2-normalize rows of A and B -> bf16 X = [nA; nB], fp32 d12[i] = nA_i . nB_i.
// Also zeroes S[8192] (2 elements per block).
__global__ __launch_bounds__(256) void ntx_nrm_kernel(const float* __restrict__ A,
                                                      const float* __restrict__ B,
                                                      unsigned short* __restrict__ X,
                                                      float* __restrict__ d12,
                                                      float* __restrict__ S) {
    const int row = blockIdx.x;
    const int t = threadIdx.x;            // 256 threads, 2 elems each
    const int lane = t & 63, wid = t >> 6;

    if (t < 2) S[row * 2 + t] = 0.f;

    const float2 av = *(const float2*)(A + row * DD + 2 * t);
    const float2 bv = *(const float2*)(B + row * DD + 2 * t);
    float sa = av.x * av.x + av.y * av.y;
    float sb = bv.x * bv.x + bv.y * bv.y;
#pragma unroll
    for (int o = 32; o; o >>= 1) { sa += __shfl_down(sa, o); sb += __shfl_down(sb, o); }

    __shared__ float red[12];
    if (lane == 0) { red[wid] = sa; red[4 + wid] = sb; }
    __syncthreads();
    const float ta = red[0] + red[1] + red[2] + red[3];
    const float tb = red[4] + red[5] + red[6] + red[7];
    const float ra = 1.f / fmaxf(sqrtf(ta), 1e-8f);
    const float rb = 1.f / fmaxf(sqrtf(tb), 1e-8f);
    const float nax = av.x * ra, nay = av.y * ra;
    const float nbx = bv.x * rb, nby = bv.y * rb;

    *(unsigned*)(X + row * DD + 2 * t) =
        (unsigned)f2bf(nax) | ((unsigned)f2bf(nay) << 16);
    *(unsigned*)(X + (NR + row) * DD + 2 * t) =
        (unsigned)f2bf(nbx) | ((unsigned)f2bf(nby) << 16);

    float dt = nax * nbx + nay * nby;
#pragma unroll
    for (int o = 32; o; o >>= 1) dt += __shfl_down(dt, o);
    if (lane == 0) red[8 + wid] = dt;
    __syncthreads();
    if (t == 0) d12[row] = red[8] + red[9] + red[10] + red[11];
}

// Kernel 2: logits[r,c] = 2 * X_r . Z_c, Z_c = X_{c^4096}.
// Round-12: 256x256 tile, 512 thr = 8 waves (2Mx4N), per-wave C = 128x64 (acc[8][4]).
// K=512 in 16 BK=32 tiles; 4 LDS buffers (128 KB); counted vmcnt(8) at each tile
// boundary (prefetch distance 3; retires exactly tile-t's 4 loads, keeps 8 in
// flight, never drains mid-loop); ONE barrier per tile; two MFMA sub-phases per
// tile with A/B staging of t+3 interleaved; setprio around MFMA clusters.
// Conflict-free slot swizzle kept (round-10: phys_slot = slot ^ ((row>>1)&3)).
// Tile triangle u<=v over 32x32, 4x4 supertiles + XCD-contiguous remap.
__global__ __launch_bounds__(512, 2) void ntx_gemm_lse_kernel(const unsigned short* __restrict__ X,
                                                              float* __restrict__ S) {
    // ---- bid -> XCD-contiguous supertile-ordered sid -> (u,v) ----
    const int bid = blockIdx.x;
    const int sid = (bid & 7) * CH2 + (bid >> 3);
    int u, v;
    if (sid < 448) {                     // off-diagonal supertile (U<V): 28 x 16
        const int s = sid >> 4, loc = sid & 15;
        int U = 0;
        while (7 * (U + 1) - (U + 1) * U / 2 <= s) ++U;      // offExcl(U+1) <= s
        const int V = U + 1 + (s - (7 * U - U * (U - 1) / 2));
        u = U * 4 + (loc >> 2);
        v = V * 4 + (loc & 3);
    } else {                             // diagonal supertile (U==V): 8 x 10, lu<=lv
        const int s2 = sid - 448;
        const int U = s2 / 10, loc = s2 % 10;
        int lu = 0;
        while ((lu + 1) * 4 - (lu + 1) * lu / 2 <= loc) ++lu; // offIncl(lu+1) <= loc
        const int lv = lu + (loc - (lu * 4 - lu * (lu - 1) / 2));
        u = U * 4 + lu;
        v = U * 4 + lv;
    }
    const bool fixedTile = (u == v);
    const int rowTile = u * 256, colTile = (v ^ 16) * 256;

    __shared__ unsigned short As[4][256 * 32];   // 4 x 16 KB
    __shared__ unsigned short Bs[4][256 * 32];   // 4 x 16 KB  (total 128 KB)

    const int t = threadIdx.x;           // 0..511
    const int lane = t & 63, wid = t >> 6;        // 8 waves
    const int waveM = wid >> 2, waveN = wid & 3;  // 2 x 4
    const int lr = lane & 15, grp = lane >> 4;
    const int swr = (lr >> 1) & 3;        // read-side swizzle key ((row>>1)&3)
    const int kslot = (grp ^ swr) * 8;    // physical 16B slot (ushorts)

    f32x4 acc[8][4] = {};

    // staging: 16 chunks of 1KB (16 rows x 64B); chunk ci = wid*2+q, q=0..1.
    // lane l -> row = ci*16 + l/4, phys slot = l&3, LDS ushort idx = ci*512 + l*8.
    // inverse source swizzle: source col = kt + ((l&3)^((l>>3)&3))*8 elems.
    const int srow = lane >> 2;                              // 0..15 within chunk
    const int scol = ((lane & 3) ^ ((lane >> 3) & 3)) * 8;   // swizzled source col

    auto STAGE_A = [&](int sel, int kt) {  // 2 VMEM instructions per thread
#pragma unroll
        for (int q = 0; q < 2; ++q) {
            const int ci = wid * 2 + q;
            const int r  = ci * 16 + srow;
            __builtin_amdgcn_global_load_lds(
                (const __attribute__((address_space(1))) unsigned*)(X + (size_t)(rowTile + r) * DD + kt + scol),
                (__attribute__((address_space(3))) unsigned*)&As[sel][ci * 512 + lane * 8], 16, 0, 0);
        }
    };
    auto STAGE_B = [&](int sel, int kt) {  // 2 VMEM instructions per thread
#pragma unroll
        for (int q = 0; q < 2; ++q) {
            const int ci = wid * 2 + q;
            const int r  = ci * 16 + srow;
            __builtin_amdgcn_global_load_lds(
                (const __attribute__((address_space(1))) unsigned*)(X + (size_t)((colTile + r) ^ NR) * DD + kt + scol),
                (__attribute__((address_space(3))) unsigned*)&Bs[sel][ci * 512 + lane * 8], 16, 0, 0);
        }
    };

    auto PHASE = [&](int sel, int mbase, bf16x8* bfr) {   // 4 ds_read + 16 MFMA
        bf16x8 af[4];
#pragma unroll
        for (int mm = 0; mm < 4; ++mm)
            af[mm] = *(const bf16x8*)&As[sel][(waveM * 128 + (mbase + mm) * 16 + lr) * 32 + kslot];
        __builtin_amdgcn_s_setprio(1);
#pragma unroll
        for (int mm = 0; mm < 4; ++mm)
#pragma unroll
            for (int n = 0; n < 4; ++n)
                acc[mbase + mm][n] = __builtin_amdgcn_mfma_f32_16x16x32_bf16(af[mm], bfr[n], acc[mbase + mm][n], 0, 0, 0);
        __builtin_amdgcn_s_setprio(0);
    };

    // ---- prologue: 3 tiles in flight (12 loads/thread) ----
    STAGE_A(0, 0);   STAGE_B(0, 0);
    STAGE_A(1, 32);  STAGE_B(1, 32);
    STAGE_A(2, 64);  STAGE_B(2, 64);

#pragma unroll
    for (int tt = 0; tt < 16; ++tt) {
        const int sel = tt & 3;
        asm volatile("s_waitcnt lgkmcnt(0)" ::: "memory");   // my reads of buf[(tt-1)&3] done
        if (tt <= 13)      asm volatile("s_waitcnt vmcnt(8)" ::: "memory");  // tile tt landed, 8 stay in flight
        else if (tt == 14) asm volatile("s_waitcnt vmcnt(4)" ::: "memory");
        else               asm volatile("s_waitcnt vmcnt(0)" ::: "memory");
        __builtin_amdgcn_s_barrier();    // all: tile tt ready AND buf[(tt+3)&3] readers done
        bf16x8 bfr[4];                   // B-frags held across both phases
#pragma unroll
        for (int n = 0; n < 4; ++n)
            bfr[n] = *(const bf16x8*)&Bs[sel][(waveN * 64 + n * 16 + lr) * 32 + kslot];
        if (tt < 13) STAGE_A((tt + 3) & 3, (tt + 3) * 32);
        PHASE(sel, 0, bfr);
        if (tt < 13) STAGE_B((tt + 3) & 3, (tt + 3) * 32);
        PHASE(sel, 4, bfr);
    }

    // ---- Epilogue ----
    // C/D layout: col = lane&15 (lr), row = grp*4 + reg.
    // 1) in-place: acc <- exp(2*acc), masked to 0 on fixed-tile local diagonal
#pragma unroll
    for (int m = 0; m < 8; ++m)
#pragma unroll
        for (int n = 0; n < 4; ++n)
#pragma unroll
            for (int reg = 0; reg < 4; ++reg) {
                const int R = rowTile + waveM * 128 + m * 16 + grp * 4 + reg;
                const int C = colTile + waveN * 64 + n * 16 + lr;
                const bool masked = fixedTile && (C == (R ^ NR));
                acc[m][n][reg] = masked ? 0.f : __expf(acc[m][n][reg] * 2.0f);
            }

    // 2) row sums -> S[R]
#pragma unroll
    for (int m = 0; m < 8; ++m)
#pragma unroll
        for (int reg = 0; reg < 4; ++reg) {
            float rs = acc[m][0][reg] + acc[m][1][reg] + acc[m][2][reg] + acc[m][3][reg];
            rs += __shfl_xor(rs, 1);
            rs += __shfl_xor(rs, 2);
            rs += __shfl_xor(rs, 4);
            rs += __shfl_xor(rs, 8);
            if (lr == 0) {
                const int R = rowTile + waveM * 128 + m * 16 + grp * 4 + reg;
                atomicAdd(&S[R], rs);
            }
        }

    // 3) mirror col sums -> S[C^N]  (skip on fixed tiles: they'd double-count)
    if (!fixedTile) {
#pragma unroll
        for (int n = 0; n < 4; ++n) {
            float cs = 0.f;
#pragma unroll
            for (int m = 0; m < 8; ++m)
#pragma unroll
                for (int reg = 0; reg < 4; ++reg)
                    cs += acc[m][n][reg];
            cs += __shfl_xor(cs, 16);
            cs += __shfl_xor(cs, 32);
            if (grp == 0) {
                const int C = colTile + waveN * 64 + n * 16 + lr;
                atomicAdd(&S[C ^ NR], cs);
            }
        }
    }
}

// Kernel 3: loss = mean_r( log(S[r]) - 2*d12[r mod N] ), float32 scalar out.
__global__ __launch_bounds__(256) void ntx_loss_kernel(const float* __restrict__ S,
                                                       const float* __restrict__ d12,
                                                       float* __restrict__ out) {
    const int t = threadIdx.x;
    float a = 0.f;
    for (int r = t; r < TWO_N; r += 256)
        a += __logf(S[r]) - 2.0f * d12[r & (NR - 1)];
    const int lane = t & 63, wid = t >> 6;
#pragma unroll
    for (int o = 32; o; o >>= 1) a += __shfl_down(a, o);
    __shared__ float red[4];
    if (lane == 0) red[wid] = a;
    __syncthreads();
    if (t == 0) out[0] = (red[0] + red[1] + red[2] + red[3]) * (1.f / (float)TWO_N);
}

extern "C" void kernel_launch(void* const* d_in, const int* in_sizes, int n_in,
                              void* d_out, int out_size, void* d_ws, size_t ws_size,
                              hipStream_t stream) {
    const float* A = (const float*)d_in[0];
    const float* B = (const float*)d_in[1];

    // workspace layout
    unsigned short* X = (unsigned short*)d_ws;                    // 8192*512*2 = 8 MB
    float* S   = (float*)((char*)d_ws + (size_t)TWO_N * DD * 2);  // 32 KB
    float* d12 = (float*)((char*)S + (size_t)TWO_N * 4);          // 16 KB

    ntx_nrm_kernel<<<NR, 256, 0, stream>>>(A, B, X, d12, S);

    ntx_gemm_lse_kernel<<<NT2, 512, 0, stream>>>(X, S);

    ntx_loss_kernel<<<1, 256, 0, stream>>>(S, d12, (float*)d_out);
}

// Round 13
// 86.870 us; speedup vs baseline: 1.0377x; 1.0377x over previous
//
#include <hip/hip_runtime.h>

#define NR 4096      // rows per batch
#define DD 512       // feature dim
#define TWO_N 8192
#define MT2 32       // 8192/256 tiles per dim
#define NT2 528      // MT2*(MT2+1)/2
#define CH2 66       // NT2/8 per XCD

using bf16x8 = __attribute__((ext_vector_type(8))) short;   // 8 bf16 in 4 VGPRs
using f32x4  = __attribute__((ext_vector_type(4))) float;

__device__ __forceinline__ unsigned short f2bf(float f) {
    union { float f; unsigned u; } v; v.f = f;
    unsigned r = v.u + 0x7fff + ((v.u >> 16) & 1);   // round-to-nearest-even
    return (unsigned short)(r >> 16);
}

// Kernel 1: L2-normalize rows of A and B -> bf16 X = [nA; nB], fp32 d12[i] = nA_i . nB_i.
// Also zeroes S[8192] (2 elements per block).
__global__ __launch_bounds__(256) void ntx_nrm_kernel(const float* __restrict__ A,
                                                      const float* __restrict__ B,
                                                      unsigned short* __restrict__ X,
                                                      float* __restrict__ d12,
                                                      float* __restrict__ S) {
    const int row = blockIdx.x;
    const int t = threadIdx.x;            // 256 threads, 2 elems each
    const int lane = t & 63, wid = t >> 6;

    if (t < 2) S[row * 2 + t] = 0.f;

    const float2 av = *(const float2*)(A + row * DD + 2 * t);
    const float2 bv = *(const float2*)(B + row * DD + 2 * t);
    float sa = av.x * av.x + av.y * av.y;
    float sb = bv.x * bv.x + bv.y * bv.y;
#pragma unroll
    for (int o = 32; o; o >>= 1) { sa += __shfl_down(sa, o); sb += __shfl_down(sb, o); }

    __shared__ float red[12];
    if (lane == 0) { red[wid] = sa; red[4 + wid] = sb; }
    __syncthreads();
    const float ta = red[0] + red[1] + red[2] + red[3];
    const float tb = red[4] + red[5] + red[6] + red[7];
    const float ra = 1.f / fmaxf(sqrtf(ta), 1e-8f);
    const float rb = 1.f / fmaxf(sqrtf(tb), 1e-8f);
    const float nax = av.x * ra, nay = av.y * ra;
    const float nbx = bv.x * rb, nby = bv.y * rb;

    *(unsigned*)(X + row * DD + 2 * t) =
        (unsigned)f2bf(nax) | ((unsigned)f2bf(nay) << 16);
    *(unsigned*)(X + (NR + row) * DD + 2 * t) =
        (unsigned)f2bf(nbx) | ((unsigned)f2bf(nby) << 16);

    float dt = nax * nbx + nay * nby;
#pragma unroll
    for (int o = 32; o; o >>= 1) dt += __shfl_down(dt, o);
    if (lane == 0) red[8 + wid] = dt;
    __syncthreads();
    if (t == 0) d12[row] = red[8] + red[9] + red[10] + red[11];
}

// Kernel 2: logits[r,c] = 2 * X_r . Z_c, Z_c = X_{c^4096}.
// Round-13: m201-style 8-phase schedule. 256x256 tile, 512 thr = 8 waves (2Mx4N),
// per-wave C = 128x64 (acc[8][4]). BK=64, 2 LDS buffers (128 KB). Per K-tile:
// 4 phases, each {ds_read quadrant regs | stage chunk of tile t+1 -> barrier ->
// lgkmcnt(0)+sched_barrier -> setprio(1) 16 MFMA setprio(0) -> barrier}.
// Quadrants (mh,nh): (0,0),(0,1),(1,1),(1,0) - phase 3 reads nothing (reg reuse).
// Boundary vmcnt(0) before tile's last barrier (also guards buffer reuse).
// BK=64 slot swizzle (round-9 proven): phys_slot = slot ^ (row&7), inverse on source.
// Triangle u<=v over 32x32 tiles, 4x4 supertiles + XCD-contiguous remap (R12 decode).
__global__ __launch_bounds__(512, 1) void ntx_gemm_lse_kernel(const unsigned short* __restrict__ X,
                                                              float* __restrict__ S) {
    // ---- bid -> XCD-contiguous supertile-ordered sid -> (u,v) ----
    const int bid = blockIdx.x;
    const int sid = (bid & 7) * CH2 + (bid >> 3);
    int u, v;
    if (sid < 448) {                     // off-diagonal supertile (U<V): 28 x 16
        const int s = sid >> 4, loc = sid & 15;
        int U = 0;
        while (7 * (U + 1) - (U + 1) * U / 2 <= s) ++U;      // offExcl(U+1) <= s
        const int V = U + 1 + (s - (7 * U - U * (U - 1) / 2));
        u = U * 4 + (loc >> 2);
        v = V * 4 + (loc & 3);
    } else {                             // diagonal supertile (U==V): 8 x 10, lu<=lv
        const int s2 = sid - 448;
        const int U = s2 / 10, loc = s2 % 10;
        int lu = 0;
        while ((lu + 1) * 4 - (lu + 1) * lu / 2 <= loc) ++lu; // offIncl(lu+1) <= loc
        const int lv = lu + (loc - (lu * 4 - lu * (lu - 1) / 2));
        u = U * 4 + lu;
        v = U * 4 + lv;
    }
    const bool fixedTile = (u == v);
    const int rowTile = u * 256, colTile = (v ^ 16) * 256;

    __shared__ unsigned short As[2][256 * 64];   // 2 x 32 KB
    __shared__ unsigned short Bs[2][256 * 64];   // 2 x 32 KB  (128 KB total)

    const int t = threadIdx.x;            // 0..511
    const int lane = t & 63, wid = t >> 6;         // 8 waves
    const int waveM = wid >> 2, waveN = wid & 3;   // 2 x 4
    const int lr = lane & 15, grp = lane >> 4;
    const int r3 = lr & 7;                // row&7 of every fragment row this lane reads

    f32x4 acc[8][4] = {};
    bf16x8 af[4][2];                      // A-frags: 4 m of current mh x 2 kk
    bf16x8 bf[4][2];                      // B-frags: all 4 n x 2 kk (both nh halves live)

    // staging: per buffer per op = 256 rows x 128B = 32 chunks of 1KB (8 rows).
    // chunk ci = wid*4 + q; lane l -> row = ci*8 + l/8, phys slot = l&7,
    // LDS ushort idx = ci*512 + l*8. Inverse source swizzle: phys p at row r holds
    // logical p^(r&7); r&7 = l>>3 here -> source col = kt + ((l&7)^(l>>3))*8 elems.
    const int srow = lane >> 3;                       // 0..7 within chunk
    const int scol = ((lane & 7) ^ srow) * 8;         // swizzled source col (elems)

    auto STAGE1 = [&](int sel, int kt, int q) {       // one A chunk + one B chunk
        const int ci = wid * 4 + q;
        const int r  = ci * 8 + srow;
        const int lo = ci * 512 + lane * 8;
        __builtin_amdgcn_global_load_lds(
            (const __attribute__((address_space(1))) unsigned*)(X + (size_t)(rowTile + r) * DD + kt + scol),
            (__attribute__((address_space(3))) unsigned*)&As[sel][lo], 16, 0, 0);
        __builtin_amdgcn_global_load_lds(
            (const __attribute__((address_space(1))) unsigned*)(X + (size_t)((colTile + r) ^ NR) * DD + kt + scol),
            (__attribute__((address_space(3))) unsigned*)&Bs[sel][lo], 16, 0, 0);
    };

    auto LDA = [&](int sel, int mh) {     // 8 ds_read_b128
#pragma unroll
        for (int mm = 0; mm < 4; ++mm)
#pragma unroll
            for (int kk = 0; kk < 2; ++kk)
                af[mm][kk] = *(const bf16x8*)&As[sel][(waveM * 128 + (mh * 4 + mm) * 16 + lr) * 64 +
                                                      (((kk * 4 + grp) ^ r3) * 8)];
    };
    auto LDB = [&](int sel, int nh) {     // 4 ds_read_b128
#pragma unroll
        for (int nn = 0; nn < 2; ++nn)
#pragma unroll
            for (int kk = 0; kk < 2; ++kk)
                bf[nh * 2 + nn][kk] = *(const bf16x8*)&Bs[sel][(waveN * 64 + (nh * 2 + nn) * 16 + lr) * 64 +
                                                               (((kk * 4 + grp) ^ r3) * 8)];
    };
    auto QUAD = [&](int mh, int nh) {     // 16 MFMA (4m x 2n x 2k)
        __builtin_amdgcn_s_setprio(1);
#pragma unroll
        for (int mm = 0; mm < 4; ++mm)
#pragma unroll
            for (int nn = 0; nn < 2; ++nn)
#pragma unroll
                for (int kk = 0; kk < 2; ++kk)
                    acc[mh * 4 + mm][nh * 2 + nn] = __builtin_amdgcn_mfma_f32_16x16x32_bf16(
                        af[mm][kk], bf[nh * 2 + nn][kk], acc[mh * 4 + mm][nh * 2 + nn], 0, 0, 0);
        __builtin_amdgcn_s_setprio(0);
    };

    // ---- prologue: stage tile 0 fully, drain, rendezvous ----
    STAGE1(0, 0, 0); STAGE1(0, 0, 1); STAGE1(0, 0, 2); STAGE1(0, 0, 3);
    asm volatile("s_waitcnt vmcnt(0)" ::: "memory");
    __builtin_amdgcn_s_barrier();

    for (int tt = 0; tt < 8; ++tt) {
        const int sel = tt & 1;
        const int kn = (tt + 1) * 64;
        // ---- phase 0: quadrant (0,0) ----
        LDA(sel, 0); LDB(sel, 0);                               // 12 ds_reads
        if (tt < 7) { STAGE1(sel ^ 1, kn, 0); STAGE1(sel ^ 1, kn, 1); }
        __builtin_amdgcn_s_barrier();
        asm volatile("s_waitcnt lgkmcnt(0)" ::: "memory");
        __builtin_amdgcn_sched_barrier(0);                      // rule #18
        QUAD(0, 0);
        __builtin_amdgcn_s_barrier();
        // ---- phase 1: quadrant (0,1) ----
        LDB(sel, 1);                                            // 4 ds_reads
        if (tt < 7) STAGE1(sel ^ 1, kn, 2);
        __builtin_amdgcn_s_barrier();
        asm volatile("s_waitcnt lgkmcnt(0)" ::: "memory");
        __builtin_amdgcn_sched_barrier(0);
        QUAD(0, 1);
        __builtin_amdgcn_s_barrier();
        // ---- phase 2: quadrant (1,1) ----
        LDA(sel, 1);                                            // 8 ds_reads
        if (tt < 7) STAGE1(sel ^ 1, kn, 3);
        __builtin_amdgcn_s_barrier();
        asm volatile("s_waitcnt lgkmcnt(0)" ::: "memory");
        __builtin_amdgcn_sched_barrier(0);
        QUAD(1, 1);
        __builtin_amdgcn_s_barrier();
        // ---- phase 3: quadrant (1,0) - all operands already in regs ----
        QUAD(1, 0);
        if (tt < 7) asm volatile("s_waitcnt vmcnt(0)" ::: "memory");  // next tile landed; buf reuse safe
        __builtin_amdgcn_s_barrier();
    }

    // ---- Epilogue ----
    // C/D layout: col = lane&15 (lr), row = grp*4 + reg.
#pragma unroll
    for (int m = 0; m < 8; ++m)
#pragma unroll
        for (int n = 0; n < 4; ++n)
#pragma unroll
            for (int reg = 0; reg < 4; ++reg) {
                const int R = rowTile + waveM * 128 + m * 16 + grp * 4 + reg;
                const int C = colTile + waveN * 64 + n * 16 + lr;
                const bool masked = fixedTile && (C == (R ^ NR));
                acc[m][n][reg] = masked ? 0.f : __expf(acc[m][n][reg] * 2.0f);
            }

    // row sums -> S[R]
#pragma unroll
    for (int m = 0; m < 8; ++m)
#pragma unroll
        for (int reg = 0; reg < 4; ++reg) {
            float rs = acc[m][0][reg] + acc[m][1][reg] + acc[m][2][reg] + acc[m][3][reg];
            rs += __shfl_xor(rs, 1);
            rs += __shfl_xor(rs, 2);
            rs += __shfl_xor(rs, 4);
            rs += __shfl_xor(rs, 8);
            if (lr == 0) {
                const int R = rowTile + waveM * 128 + m * 16 + grp * 4 + reg;
                atomicAdd(&S[R], rs);
            }
        }

    // mirror col sums -> S[C^N]  (skip on fixed tiles: they'd double-count)
    if (!fixedTile) {
#pragma unroll
        for (int n = 0; n < 4; ++n) {
            float cs = 0.f;
#pragma unroll
            for (int m = 0; m < 8; ++m)
#pragma unroll
                for (int reg = 0; reg < 4; ++reg)
                    cs += acc[m][n][reg];
            cs += __shfl_xor(cs, 16);
            cs += __shfl_xor(cs, 32);
            if (grp == 0) {
                const int C = colTile + waveN * 64 + n * 16 + lr;
                atomicAdd(&S[C ^ NR], cs);
            }
        }
    }
}

// Kernel 3: loss partials: 32 blocks x 256 thr, one r each; block-reduce then
// atomicAdd(out, partial/2N). d_out is zeroed via hipMemsetAsync each call.
__global__ __launch_bounds__(256) void ntx_loss_kernel(const float* __restrict__ S,
                                                       const float* __restrict__ d12,
                                                       float* __restrict__ out) {
    const int t = threadIdx.x;
    const int r = blockIdx.x * 256 + t;
    float a = __logf(S[r]) - 2.0f * d12[r & (NR - 1)];
    const int lane = t & 63, wid = t >> 6;
#pragma unroll
    for (int o = 32; o; o >>= 1) a += __shfl_down(a, o);
    __shared__ float red[4];
    if (lane == 0) red[wid] = a;
    __syncthreads();
    if (t == 0) atomicAdd(out, (red[0] + red[1] + red[2] + red[3]) * (1.f / (float)TWO_N));
}

extern "C" void kernel_launch(void* const* d_in, const int* in_sizes, int n_in,
                              void* d_out, int out_size, void* d_ws, size_t ws_size,
                              hipStream_t stream) {
    const float* A = (const float*)d_in[0];
    const float* B = (const float*)d_in[1];

    // workspace layout
    unsigned short* X = (unsigned short*)d_ws;                    // 8192*512*2 = 8 MB
    float* S   = (float*)((char*)d_ws + (size_t)TWO_N * DD * 2);  // 32 KB
    float* d12 = (float*)((char*)S + (size_t)TWO_N * 4);          // 16 KB

    hipMemsetAsync(d_out, 0, sizeof(float), stream);              // loss accumulator

    ntx_nrm_kernel<<<NR, 256, 0, stream>>>(A, B, X, d12, S);

    ntx_gemm_lse_kernel<<<NT2, 512, 0, stream>>>(X, S);

    ntx_loss_kernel<<<TWO_N / 256, 256, 0, stream>>>(S, d12, (float*)d_out);
}